// Round 7
// baseline (1805.667 us; speedup 1.0000x reference)
//
#include <hip/hip_runtime.h>
#include <hip/hip_bf16.h>
#include <stdint.h>

#define DEVINL __device__ __forceinline__

typedef __attribute__((ext_vector_type(8))) short short8;
typedef __attribute__((ext_vector_type(4))) float float4v;
typedef __attribute__((ext_vector_type(4))) int int4v;

// Problem constants: V=50000, T=32, E=256, HID=512, H=256, L=512, B=64
// xproj stores preact * NL (i,f,o) or * 2NL (g), NL = -log2(e), so the LSTM
// inner loop needs only native v_exp_f32 / v_rcp_f32.
#define NLC (-1.4426950408889634f)

DEVINL float uif(unsigned u) { union { unsigned u; float f; } v; v.u = u; return v.f; }
DEVINL float bf2f(short s) { return uif(((unsigned)(unsigned short)s) << 16); }
DEVINL unsigned short f2bf(float f) {
  union { float f; unsigned u; } v; v.f = f;
  unsigned r = v.u + 0x7FFFu + ((v.u >> 16) & 1u);  // RNE
  return (unsigned short)(r >> 16);
}
DEVINL unsigned cvt_pk_bf16(float lo, float hi) {
  unsigned r;
  asm("v_cvt_pk_bf16_f32 %0, %1, %2" : "=v"(r) : "v"(lo), "v"(hi));
  return r;
}
DEVINL float ex2(float x) { return __builtin_amdgcn_exp2f(x); }
DEVINL float rcp_(float x) { return __builtin_amdgcn_rcpf(x); }
// unpack 4 bf16 from a packed 64-bit word (1 inst per value)
DEVINL void unp4(unsigned long long u, float* f) {
  unsigned lo = (unsigned)u, hi = (unsigned)(u >> 32);
  f[0] = uif(lo << 16); f[1] = uif(lo & 0xffff0000u);
  f[2] = uif(hi << 16); f[3] = uif(hi & 0xffff0000u);
}

#define LBAR() do { \
  asm volatile("s_waitcnt lgkmcnt(0)" ::: "memory"); \
  __builtin_amdgcn_sched_barrier(0); \
  __builtin_amdgcn_s_barrier(); \
  __builtin_amdgcn_sched_barrier(0); \
} while (0)

// ---------------- K0: f32 -> bf16 converts ----------------
__global__ void k_cvt(const float* __restrict__ src, short* __restrict__ dst, int n8) {
  int i = blockIdx.x * blockDim.x + threadIdx.x;
  int stride = gridDim.x * blockDim.x;
  for (; i < n8; i += stride) {
    const float4v* s = (const float4v*)(src + (size_t)i * 8);
    float4v a = s[0], b = s[1];
    short8 o;
    o[0] = (short)f2bf(a[0]); o[1] = (short)f2bf(a[1]);
    o[2] = (short)f2bf(a[2]); o[3] = (short)f2bf(a[3]);
    o[4] = (short)f2bf(b[0]); o[5] = (short)f2bf(b[1]);
    o[6] = (short)f2bf(b[2]); o[7] = (short)f2bf(b[3]);
    ((short8*)dst)[i] = o;
  }
}

__global__ void k_bias(const float* __restrict__ a1, const float* __restrict__ a2,
                       const float* __restrict__ b1, const float* __restrict__ b2,
                       float* __restrict__ o) {
  int i = blockIdx.x * blockDim.x + threadIdx.x;  // 0..2047
  o[i] = (i < 1024) ? (a1[i] + a2[i]) : (b1[i - 1024] + b2[i - 1024]);
}

// ---------------- K-wmax: per-direction max|W_hh| ----------------
__global__ void k_wmax(const float* __restrict__ Wf, const float* __restrict__ Wb,
                       unsigned* __restrict__ wmax) {
  int i = blockIdx.x * blockDim.x + threadIdx.x;
  int stride = gridDim.x * blockDim.x;
  unsigned mf = 0, mb = 0;
  for (int k = i; k < 262144; k += stride) {
    mf = max(mf, __float_as_uint(fabsf(Wf[k])));
    mb = max(mb, __float_as_uint(fabsf(Wb[k])));
  }
#pragma unroll
  for (int o = 32; o > 0; o >>= 1) {
    mf = max(mf, (unsigned)__shfl_down((int)mf, o));
    mb = max(mb, (unsigned)__shfl_down((int)mb, o));
  }
  if ((threadIdx.x & 63) == 0) { atomicMax(wmax + 0, mf); atomicMax(wmax + 1, mb); }
}

// ---------------- K-wquant: W_hh f32 -> int8 MFMA fragments (layout verified R3) ------
__global__ void k_wquant(const float* __restrict__ Wf, const float* __restrict__ Wb,
                         const float* __restrict__ wmax, char* __restrict__ whhQ) {
  int idx = blockIdx.x * blockDim.x + threadIdx.x;  // 0..131071 (quad of k)
  int dir = idx >> 16;
  int rem = idx & 65535;
  int r = rem >> 6;          // 0..1023 = g*256+unit
  int k = (rem & 63) * 4;
  const float* W = dir ? Wb : Wf;
  float s = 127.0f / fmaxf(wmax[dir], 1e-20f);
  int g = r >> 8, unit = r & 255;
  int w = unit >> 6, m = (unit >> 4) & 3, row = unit & 15;
  int kt = k >> 6, l4 = (k >> 4) & 3, j = k & 15;
  int lane = l4 * 16 + row;
  unsigned out = 0;
#pragma unroll
  for (int t = 0; t < 4; ++t) {
    float v = W[(size_t)r * 256 + k + t] * s;
    int q = (int)rintf(v);
    q = q < -127 ? -127 : (q > 127 ? 127 : q);
    out |= ((unsigned)(q & 255)) << (8 * t);
  }
  *(unsigned*)(whhQ + (size_t)dir * 262144 + g * 65536 + w * 16384 + m * 4096 + kt * 1024 + lane * 16 + j) = out;
}

// ---------------- K1: x_proj, A staged once per WG, 16 B-tiles looped ----------------
__launch_bounds__(256)
__global__ void k_xproj(const int* __restrict__ seqs, const short* __restrict__ embT,
                        const short* __restrict__ wihX, const float* __restrict__ biasX,
                        short* __restrict__ xproj) {
  __shared__ short As[128 * 256];
  __shared__ short Bs[128 * 256];
  __shared__ int ids[128];
  const int bm = blockIdx.x;
  const int tid = threadIdx.x;
  if (tid < 128) ids[tid] = seqs[bm * 128 + tid];
  __syncthreads();
#pragma unroll
  for (int i = 0; i < 16; ++i) {  // stage A (gathered embeddings) ONCE
    int task = tid + i * 256, row = task >> 5, kc = task & 31;
    short8 v = *(const short8*)(embT + (size_t)ids[row] * 256 + kc * 8);
    *(short8*)((char*)As + row * 512 + ((kc * 16) ^ ((row & 7) << 4))) = v;
  }
  __syncthreads();
  const int wave = tid >> 6, lane = tid & 63, l15 = lane & 15, l4 = lane >> 4;
  // hoist A fragments to registers (64 VGPR)
  short8 af[2][8];
#pragma unroll
  for (int m = 0; m < 2; ++m) {
    int row = (wave * 2 + m) * 16 + l15;
#pragma unroll
    for (int kt = 0; kt < 8; ++kt)
      af[m][kt] = *(short8*)((char*)As + row * 512 + ((kt * 64 + l4 * 16) ^ ((row & 7) << 4)));
  }
#pragma unroll 1
  for (int bn = 0; bn < 16; ++bn) {
    __syncthreads();  // previous compute done reading Bs
#pragma unroll
    for (int i = 0; i < 16; ++i) {
      int task = tid + i * 256, row = task >> 5, kc = task & 31;
      short8 v = *(const short8*)(wihX + (size_t)(bn * 128 + row) * 256 + kc * 8);
      *(short8*)((char*)Bs + row * 512 + ((kc * 16) ^ ((row & 7) << 4))) = v;
    }
    __syncthreads();
    float4v acc[2][8];
#pragma unroll
    for (int m = 0; m < 2; ++m)
#pragma unroll
      for (int n = 0; n < 8; ++n) acc[m][n] = (float4v){0.f, 0.f, 0.f, 0.f};
#pragma unroll
    for (int kt = 0; kt < 8; ++kt) {
      const int kb = kt * 64 + l4 * 16;
      short8 b[8];
#pragma unroll
      for (int n = 0; n < 8; ++n) {
        int row = n * 16 + l15;
        b[n] = *(short8*)((char*)Bs + row * 512 + (kb ^ ((row & 7) << 4)));
      }
#pragma unroll
      for (int m = 0; m < 2; ++m)
#pragma unroll
        for (int n = 0; n < 8; ++n)
          acc[m][n] = __builtin_amdgcn_mfma_f32_16x16x32_bf16(af[m][kt], b[n], acc[m][n], 0, 0, 0);
    }
#pragma unroll
    for (int n = 0; n < 8; ++n) {
      int col = bn * 128 + n * 16 + l15;
      float bias = biasX[col];
      float scale = (((col >> 8) & 3) == 2) ? (2.f * NLC) : NLC;  // g-gate vs i,f,o
#pragma unroll
      for (int m = 0; m < 2; ++m) {
        int token = bm * 128 + (wave * 2 + m) * 16 + l4 * 4;
#pragma unroll
        for (int q = 0; q < 4; ++q)
          xproj[(size_t)(token + q) * 2048 + col] = (short)f2bf((acc[m][n][q] + bias) * scale);
      }
    }
  }
}

// ---------------- K2: bidirectional LSTM recurrence, fully WG-local ----------------
// 8 WGs = dir x batch-quarter. 1024 threads = 16 waves (4/SIMD for latency hiding).
// Wave w owns units [w*16, w*16+16); int8 W_hh fragments resident (64 VGPR/lane).
// h int8 double-buffered in LDS, one lgkm-only barrier/substep. Pointer-bump
// addressing + register ping-pong for the xproj prefetch.
__launch_bounds__(1024, 1)
__global__ void k_lstm(const short* __restrict__ xproj, const char* __restrict__ whhQ,
                       const float* __restrict__ wmax, const int* __restrict__ mask_ws,
                       short* __restrict__ h_all) {
  __shared__ char lds_h[2][16 * 256];
  const int bid = blockIdx.x;
  const int dir = bid & 1, bq = bid >> 1;
  const int tid = threadIdx.x, w = tid >> 6, lane = tid & 63;
  const int beta = lane & 15, l4 = lane >> 4;
  const int bglob = bq * 16 + beta;
  const float wm = wmax[dir] * (1.0f / 16129.0f);
  const float facS = wm * NLC;
  const float facG = wm * 2.f * NLC;

  // stationary int8 W_hh fragments: wave w = unit-tile w (units w*16..w*16+15)
  int4v wf[4][4];
  {
    const char* base = whhQ + (size_t)dir * 262144 + (w >> 2) * 16384 + (w & 3) * 4096 + lane * 16;
#pragma unroll
    for (int g = 0; g < 4; ++g)
#pragma unroll
      for (int kt = 0; kt < 4; ++kt)
        wf[g][kt] = *(const int4v*)(base + g * 65536 + kt * 1024);
  }

  int rd_off[4];
#pragma unroll
  for (int kt = 0; kt < 4; ++kt)
    rd_off[kt] = beta * 256 + ((kt * 64 + l4 * 16) ^ ((beta & 7) << 4));
  const int wr_off = beta * 256 + ((w * 16 + l4 * 4) ^ ((beta & 7) << 4));

  if (tid < 256) ((int4v*)lds_h[0])[tid] = (int4v){0, 0, 0, 0};

  float c[4], hq[4];
#pragma unroll
  for (int q = 0; q < 4; ++q) { c[q] = 0.f; hq[q] = 0.f; }

  // carried pointers, bumped by wave-uniform strides (guard regions in d_ws
  // absorb the one-step-past prefetch at both sequence ends)
  const int t0 = dir ? 511 : 0;
  const int SD = dir ? -131072 : 131072;   // xproj shorts per step
  const int SM = dir ? -64 : 64;           // mask ints per step
  const int SH = dir ? -32768 : 32768;     // h_all shorts per step
  const short* px = xproj + (size_t)(t0 * 64 + bglob) * 2048 + dir * 1024 + w * 16 + l4 * 4;
  const int* pm = mask_ws + t0 * 64 + bglob;
  short* ph = h_all + (size_t)(t0 * 64 + bglob) * 512 + dir * 256 + w * 16 + l4 * 4;

  unsigned long long X0[4], X1[4];
  int m0, m1;
#pragma unroll
  for (int g = 0; g < 4; ++g)
    X0[g] = *(const unsigned long long*)(px + g * 256);
  m0 = *pm;
  px += SD; pm += SM;

  auto SUB = [&](unsigned long long (&xc)[4], int& mc,
                 unsigned long long (&xn)[4], int& mn,
                 const char* rb, char* wb) {
    LBAR();  // prev substep's LDS writes visible
    int4v bfr[4];
#pragma unroll
    for (int kt = 0; kt < 4; ++kt) bfr[kt] = *(const int4v*)(rb + rd_off[kt]);

    // prefetch next step (immediate offsets off one carried pointer)
#pragma unroll
    for (int g = 0; g < 4; ++g)
      xn[g] = *(const unsigned long long*)(px + g * 256);
    mn = *pm;
    px += SD; pm += SM;

    // recurrent GEMM (int8, K=64): 16 MFMAs, 4 independent 4-chains
    int4v iacc[4];
#pragma unroll
    for (int g = 0; g < 4; ++g) {
      int4v t = __builtin_amdgcn_mfma_i32_16x16x64_i8(wf[g][0], bfr[0], (int4v){0, 0, 0, 0}, 0, 0, 0);
      t = __builtin_amdgcn_mfma_i32_16x16x64_i8(wf[g][1], bfr[1], t, 0, 0, 0);
      t = __builtin_amdgcn_mfma_i32_16x16x64_i8(wf[g][2], bfr[2], t, 0, 0, 0);
      iacc[g] = __builtin_amdgcn_mfma_i32_16x16x64_i8(wf[g][3], bfr[3], t, 0, 0, 0);
    }

    float xi[4], xf[4], xg[4], xo[4];
    unp4(xc[0], xi); unp4(xc[1], xf); unp4(xc[2], xg); unp4(xc[3], xo);
    unsigned qb[4]; float ov[4];
#pragma unroll
    for (int q = 0; q < 4; ++q) {
      float ai = fmaf((float)iacc[0][q], facS, xi[q]);
      float af_ = fmaf((float)iacc[1][q], facS, xf[q]);
      float ag = fmaf((float)iacc[2][q], facG, xg[q]);
      float ao = fmaf((float)iacc[3][q], facS, xo[q]);
      float Ei = ex2(ai);                    // inf-safe: rcp(inf)=0 limits are exact
      float Ef = ex2(af_);
      float Eg = fminf(ex2(ag), 1e30f);      // cap: appears in (1-Eg)
      float Eo = ex2(ao);
      float t1 = 1.f + Ei;
      float ig = (1.f - Eg) * rcp_(fmaf(t1, Eg, t1));          // sigmoid(i)*tanh(g)
      float fv = rcp_(1.f + Ef);
      float cn = fmaf(fv, c[q], ig);
      float Ec = fminf(ex2(cn * (2.f * NLC)), 1e30f);          // cap: appears in (1-Ec)
      float t2 = 1.f + Eo;
      float hn = (1.f - Ec) * rcp_(fmaf(t2, Ec, t2));          // sigmoid(o)*tanh(c)
      c[q] = mc ? cn : c[q];
      float hv = mc ? hn : hq[q];
      hq[q] = hv;
      ov[q] = mc ? hn : 0.f;
      qb[q] = __float_as_uint(fmaf(hv, 127.f, 12582912.f));    // low byte = int8(h*127)
    }
    unsigned p0 = __builtin_amdgcn_perm(qb[1], qb[0], 0x0c0c0400u);
    unsigned p1 = __builtin_amdgcn_perm(qb[3], qb[2], 0x0c0c0400u);
    unsigned qpack = __builtin_amdgcn_perm(p1, p0, 0x05040100u);
    *(unsigned*)(wb + wr_off) = qpack;
    uint2 ob;
    ob.x = cvt_pk_bf16(ov[0], ov[1]);
    ob.y = cvt_pk_bf16(ov[2], ov[3]);
    *(uint2*)ph = ob;
    ph += SH;
  };

#pragma unroll 1
  for (int s2 = 0; s2 < 256; ++s2) {
    SUB(X0, m0, X1, m1, lds_h[0], lds_h[1]);
    SUB(X1, m1, X0, m0, lds_h[1], lds_h[0]);
  }
}

// ---------------- K3: emissions = h_all·W_outᵀ + b_out (f32) ----------------
__launch_bounds__(256)
__global__ void k_emis(const short* __restrict__ h_all, const short* __restrict__ woutX,
                       const float* __restrict__ bout, float* __restrict__ emis) {
  const int tid = threadIdx.x, wave = tid >> 6, lane = tid & 63;
  const int l15 = lane & 15, l4 = lane >> 4;
  const int token0 = blockIdx.x * 256 + wave * 64;
  float4v acc[4][2];
#pragma unroll
  for (int m = 0; m < 4; ++m)
#pragma unroll
    for (int n = 0; n < 2; ++n) acc[m][n] = (float4v){0.f, 0.f, 0.f, 0.f};
#pragma unroll
  for (int kt = 0; kt < 16; ++kt) {
    short8 b[2];
#pragma unroll
    for (int n = 0; n < 2; ++n)
      b[n] = *(const short8*)(woutX + (size_t)(n * 16 + l15) * 512 + kt * 32 + l4 * 8);
#pragma unroll
    for (int m = 0; m < 4; ++m) {
      short8 a = *(const short8*)(h_all + (size_t)(token0 + m * 16 + l15) * 512 + kt * 32 + l4 * 8);
#pragma unroll
      for (int n = 0; n < 2; ++n)
        acc[m][n] = __builtin_amdgcn_mfma_f32_16x16x32_bf16(a, b[n], acc[m][n], 0, 0, 0);
    }
  }
#pragma unroll
  for (int n = 0; n < 2; ++n) {
    float bias = bout[n * 16 + l15];
#pragma unroll
    for (int m = 0; m < 4; ++m) {
      int token = token0 + m * 16 + l4 * 4;
#pragma unroll
      for (int q = 0; q < 4; ++q)
        emis[(size_t)(token + q) * 32 + n * 16 + l15] = acc[m][n][q] + bias;
    }
  }
}

// ---------------- K4: CRF numerator + partition scan + final reduce ----------------
__launch_bounds__(64)
__global__ void k_crf(const float* __restrict__ emis, const int* __restrict__ tags,
                      const int* __restrict__ masks, const float* __restrict__ strans,
                      const float* __restrict__ etrans, const float* __restrict__ trans,
                      float* __restrict__ out) {
  __shared__ float trans_s[1024];
  __shared__ float score_s[32];
  const float L2E = 1.4426950408889634f;
  const int b = blockIdx.x, lane = threadIdx.x;
  for (int i = lane; i < 1024; i += 64) trans_s[i] = trans[i];

  float num = 0.f; int lensum = 0;
#pragma unroll 1
  for (int i = 0; i < 8; ++i) {
    int t = lane + i * 64;
    int tg = tags[t * 64 + b];
    int m = masks[t * 64 + b];
    lensum += m;
    float e = emis[(size_t)(t * 64 + b) * 32 + tg];
    if (t == 0) num += strans[tg] + e;
    else if (m) num += e + trans[tags[(t - 1) * 64 + b] * 32 + tg];
  }
#pragma unroll
  for (int o = 32; o > 0; o >>= 1) { num += __shfl_down(num, o); lensum += __shfl_down(lensum, o); }
  num = __shfl(num, 0);
  lensum = __shfl(lensum, 0);
  num += etrans[tags[(lensum - 1) * 64 + b]];
  __syncthreads();

  const int jp = lane & 31, half = lane >> 5;
  if (lane < 32) score_s[jp] = strans[jp] + emis[(size_t)b * 32 + jp];
  __syncthreads();

  float e_next = emis[(size_t)(64 + b) * 32 + jp];
#pragma unroll 1
  for (int t = 1; t < 512; ++t) {
    float e = e_next;
    if (t < 511) e_next = emis[(size_t)((t + 1) * 64 + b) * 32 + jp];
    int m = masks[t * 64 + b];
    float v[16], mx = -1e30f;
#pragma unroll
    for (int j = 0; j < 16; ++j) {
      v[j] = score_s[half * 16 + j] + trans_s[(half * 16 + j) * 32 + jp];
      mx = fmaxf(mx, v[j]);
    }
    float sum = 0.f;
#pragma unroll
    for (int j = 0; j < 16; ++j) sum += ex2((v[j] - mx) * L2E);
    float mo = __shfl_xor(mx, 32), so = __shfl_xor(sum, 32);
    float mn2 = fmaxf(mx, mo);
    sum = sum * ex2((mx - mn2) * L2E) + so * ex2((mo - mn2) * L2E);
    float nxt = e + mn2 + __builtin_amdgcn_logf(sum) * (1.f / L2E);
    float cur = score_s[jp];
    float ns = m ? nxt : cur;
    __syncthreads();
    if (lane < 32) score_s[jp] = ns;
    __syncthreads();
  }

  float vv = (lane < 32) ? (score_s[jp] + etrans[jp]) : -1e30f;
  float mx = vv;
#pragma unroll
  for (int o = 32; o > 0; o >>= 1) mx = fmaxf(mx, __shfl_xor(mx, o));
  float sm = (lane < 32) ? ex2((vv - mx) * L2E) : 0.f;
#pragma unroll
  for (int o = 32; o > 0; o >>= 1) sm += __shfl_xor(sm, o);
  float lz = mx + __builtin_amdgcn_logf(sm) * (1.f / L2E);
  if (lane == 0) atomicAdd(out, -(num - lz) * (1.0f / 64.0f));
}

// ---------------- launch ----------------
extern "C" void kernel_launch(void* const* d_in, const int* in_sizes, int n_in,
                              void* d_out, int out_size, void* d_ws, size_t ws_size,
                              hipStream_t stream) {
  const int*   seqs  = (const int*)d_in[0];
  const int*   tags  = (const int*)d_in[1];
  const int*   masks = (const int*)d_in[2];
  const float* embed = (const float*)d_in[3];
  const float* Wihf  = (const float*)d_in[4];
  const float* Whhf  = (const float*)d_in[5];
  const float* bihf  = (const float*)d_in[6];
  const float* bhhf  = (const float*)d_in[7];
  const float* Wihb  = (const float*)d_in[8];
  const float* Whhb  = (const float*)d_in[9];
  const float* bihb  = (const float*)d_in[10];
  const float* bhhb  = (const float*)d_in[11];
  const float* Wout  = (const float*)d_in[12];
  const float* bout  = (const float*)d_in[13];
  const float* strn  = (const float*)d_in[14];
  const float* etrn  = (const float*)d_in[15];
  const float* trn   = (const float*)d_in[16];
  float* outf = (float*)d_out;

  char* ws = (char*)d_ws;
  // [0, 262144): guard for k_lstm's one-step-past prefetch (dir=1)
  short* xproj = (short*)(ws + 262144);          // 134,217,728 B (dir=0 overread -> h_all, fine)
  short* h_all = (short*)(ws + 134479872);       //  33,554,432 B
  float* emis  = (float*)(ws + 168034304);       //   4,194,304 B
  short* embT  = (short*)(ws + 172228608);       //  25,600,000 B
  short* wihX  = (short*)(ws + 197828608);       //   1,048,576 B
  char*  whhQ  = (char*)(ws + 198877184);        //     524,288 B
  short* woutX = (short*)(ws + 199401472);       //      32,768 B
  float* biasX = (float*)(ws + 199434240);       //       8,192 B
  unsigned* wmaxb = (unsigned*)(ws + 199442432); //       256 B
  int* mask_ws = (int*)(ws + 199442944);         // 131,072 B (+256 B guards both sides)

  hipMemsetAsync(d_out, 0, 4, stream);
  hipMemsetAsync(wmaxb, 0, 8, stream);
  hipMemcpyAsync(mask_ws, masks, 131072, hipMemcpyDeviceToDevice, stream);

  k_cvt<<<2048, 256, 0, stream>>>(embed, embT, 1600000);
  k_cvt<<<128, 256, 0, stream>>>(Wihf, wihX, 32768);
  k_cvt<<<128, 256, 0, stream>>>(Wihb, wihX + 262144, 32768);
  k_cvt<<<8, 256, 0, stream>>>(Wout, woutX, 2048);
  k_bias<<<2, 1024, 0, stream>>>(bihf, bhhf, bihb, bhhb, biasX);
  k_wmax<<<64, 256, 0, stream>>>(Whhf, Whhb, wmaxb);
  k_wquant<<<512, 256, 0, stream>>>(Whhf, Whhb, (const float*)wmaxb, whhQ);
  k_xproj<<<256, 256, 0, stream>>>(seqs, embT, wihX, biasX, xproj);
  k_lstm<<<8, 1024, 0, stream>>>(xproj, whhQ, (const float*)wmaxb, mask_ws, h_all);
  k_emis<<<128, 256, 0, stream>>>(h_all, woutX, bout, emis);
  k_crf<<<64, 64, 0, stream>>>(emis, tags, masks, strn, etrn, trn, outf);
}